// Round 1
// baseline (26774.084 us; speedup 1.0000x reference)
//
#include <hip/hip_runtime.h>
#include <math.h>

// KNNGraph(2) on N=16384 points, D=64, fp32.
// adjacency = I + one-hot(nearest other neighbor) per row.
// argmin_j (sq[j] - 2*dot(x_i,x_j)), j != i  (sq[i] term is row-constant).

#define NPTS 16384
#define DIM 64
#define BM 128          // rows per block
#define BN 64           // cols per j-tile
#define TM 8            // rows per thread
#define TN 4            // cols per thread
#define NTHR 256        // 16x16 thread layout
#define JSPLIT 4        // split j-range for occupancy (2 blocks/CU)
#define JRANGE (NPTS / JSPLIT)   // 4096
#define NJT (JRANGE / BN)        // 64 tiles
#define LS 68           // LDS row stride in floats: 272 B = 16B aligned, bank-spread

__global__ void sq_kernel(const float* __restrict__ X, float* __restrict__ sqout) {
  int i = blockIdx.x * NTHR + threadIdx.x;
  const float4* x4 = (const float4*)(X + (size_t)i * DIM);
  float s = 0.f;
#pragma unroll
  for (int k = 0; k < DIM / 4; ++k) {
    float4 v = x4[k];
    s = fmaf(v.x, v.x, s); s = fmaf(v.y, v.y, s);
    s = fmaf(v.z, v.z, s); s = fmaf(v.w, v.w, s);
  }
  sqout[i] = s;
}

__global__ __launch_bounds__(NTHR, 2) void knn_kernel(
    const float* __restrict__ X, const float* __restrict__ sqn,
    float* __restrict__ out, float* __restrict__ cand_val, int* __restrict__ cand_idx) {
  __shared__ float As[BM * LS];   // 34816 B
  __shared__ float Bs[BN * LS];   // 17408 B
  __shared__ float sqt[BN];

  const int tid = threadIdx.x;
  const int tx = tid & 15;
  const int ty = tid >> 4;
  const int ib = blockIdx.x >> 2;   // / JSPLIT
  const int jh = blockIdx.x & 3;    // % JSPLIT
  const int i0 = ib * BM;
  const int j0base = jh * JRANGE;

  // Stage A tile (BM x DIM) once: coalesced float4 loads.
  {
    const float4* src = (const float4*)(X + (size_t)i0 * DIM);
#pragma unroll
    for (int p = 0; p < (BM * DIM / 4) / NTHR; ++p) {
      int f4 = tid + NTHR * p;
      int r = f4 >> 4, c = f4 & 15;   // 16 float4 per row
      float4 v = src[f4];
      *(float4*)(&As[r * LS + c * 4]) = v;
    }
  }

  float bestv[TM];
  int besti[TM];
#pragma unroll
  for (int mk = 0; mk < TM; ++mk) { bestv[mk] = INFINITY; besti[mk] = 0x7fffffff; }

  for (int jt = 0; jt < NJT; ++jt) {
    const int j0 = j0base + jt * BN;
    __syncthreads();   // protect Bs from previous iteration's readers
    // Stage B tile (BN x DIM)
    {
      const float4* src = (const float4*)(X + (size_t)j0 * DIM);
#pragma unroll
      for (int p = 0; p < (BN * DIM / 4) / NTHR; ++p) {
        int f4 = tid + NTHR * p;
        int r = f4 >> 4, c = f4 & 15;
        float4 v = src[f4];
        *(float4*)(&Bs[r * LS + c * 4]) = v;
      }
      if (tid < BN) sqt[tid] = sqn[j0 + tid];
    }
    __syncthreads();

    // Zero this block's output stripe for this tile (BM x BN) AFTER the
    // barrier: hipcc drains vmcnt(0) before every s_barrier, so stores
    // issued here retire during the GEMM below and drain at the NEXT
    // iteration's barrier instead of stalling this one. Result-identical:
    // nothing reads `out` until merge_kernel (stream-ordered).
    {
#pragma unroll
      for (int p = 0; p < (BM * BN / 4) / NTHR; ++p) {
        int f4 = tid + NTHR * p;
        int r = f4 >> 4;      // BN/4 = 16 float4 per row
        int c = f4 & 15;
        *(float4*)(out + (size_t)(i0 + r) * NPTS + j0 + c * 4) =
            make_float4(0.f, 0.f, 0.f, 0.f);
      }
    }

    float acc[TM][TN];
#pragma unroll
    for (int mk = 0; mk < TM; ++mk)
#pragma unroll
      for (int nk = 0; nk < TN; ++nk) acc[mk][nk] = 0.f;

#pragma unroll
    for (int d0 = 0; d0 < DIM; d0 += 4) {
      float4 a[TM], b[TN];
#pragma unroll
      for (int mk = 0; mk < TM; ++mk)
        a[mk] = *(const float4*)(&As[(ty + 16 * mk) * LS + d0]);
#pragma unroll
      for (int nk = 0; nk < TN; ++nk)
        b[nk] = *(const float4*)(&Bs[(tx + 16 * nk) * LS + d0]);
#pragma unroll
      for (int mk = 0; mk < TM; ++mk)
#pragma unroll
        for (int nk = 0; nk < TN; ++nk) {
          acc[mk][nk] = fmaf(a[mk].x, b[nk].x, acc[mk][nk]);
          acc[mk][nk] = fmaf(a[mk].y, b[nk].y, acc[mk][nk]);
          acc[mk][nk] = fmaf(a[mk].z, b[nk].z, acc[mk][nk]);
          acc[mk][nk] = fmaf(a[mk].w, b[nk].w, acc[mk][nk]);
        }
    }

    // Update running argmin (j visited in increasing order per thread).
#pragma unroll
    for (int nk = 0; nk < TN; ++nk) {
      const int j = j0 + tx + 16 * nk;
      const float sj = sqt[tx + 16 * nk];
#pragma unroll
      for (int mk = 0; mk < TM; ++mk) {
        const int irow = i0 + ty + 16 * mk;
        float v = fmaf(-2.f, acc[mk][nk], sj);
        if (j != irow && (v < bestv[mk] || (v == bestv[mk] && j < besti[mk]))) {
          bestv[mk] = v;
          besti[mk] = j;
        }
      }
    }
  }

  // Cross-thread reduction: row m is owned by the 16 tx-threads of its ty.
  __syncthreads();
  float* rv = As;        // [BM][16] floats (8 KB, fits in As)
  int* ri = (int*)Bs;    // [BM][16] ints  (8 KB, fits in Bs)
#pragma unroll
  for (int mk = 0; mk < TM; ++mk) {
    int m = ty + 16 * mk;
    rv[m * 16 + tx] = bestv[mk];
    ri[m * 16 + tx] = besti[mk];
  }
  __syncthreads();
  if (tid < BM) {
    float bv = INFINITY;
    int bi = 0x7fffffff;
#pragma unroll
    for (int t = 0; t < 16; ++t) {
      float v = rv[tid * 16 + t];
      int ix = ri[tid * 16 + t];
      if (v < bv || (v == bv && ix < bi)) { bv = v; bi = ix; }
    }
    cand_val[(size_t)(i0 + tid) * JSPLIT + jh] = bv;
    cand_idx[(size_t)(i0 + tid) * JSPLIT + jh] = bi;
  }
}

__global__ void merge_kernel(const float* __restrict__ cand_val,
                             const int* __restrict__ cand_idx,
                             float* __restrict__ out) {
  int i = blockIdx.x * NTHR + threadIdx.x;
  float bv = INFINITY;
  int bi = 0x7fffffff;
#pragma unroll
  for (int s = 0; s < JSPLIT; ++s) {
    float v = cand_val[(size_t)i * JSPLIT + s];
    int ix = cand_idx[(size_t)i * JSPLIT + s];
    if (v < bv || (v == bv && ix < bi)) { bv = v; bi = ix; }
  }
  out[(size_t)i * NPTS + i] = 1.0f;   // self is always nearest (dist ~ 0)
  out[(size_t)i * NPTS + bi] = 1.0f;  // nearest other neighbor
}

extern "C" void kernel_launch(void* const* d_in, const int* in_sizes, int n_in,
                              void* d_out, int out_size, void* d_ws, size_t ws_size,
                              hipStream_t stream) {
  const float* X = (const float*)d_in[0];
  float* out = (float*)d_out;

  // Workspace layout: sq[N] | cand_val[N*JSPLIT] | cand_idx[N*JSPLIT]  (~576 KB)
  float* sq = (float*)d_ws;
  float* cand_val = sq + NPTS;
  int* cand_idx = (int*)(cand_val + (size_t)NPTS * JSPLIT);

  sq_kernel<<<NPTS / NTHR, NTHR, 0, stream>>>(X, sq);
  knn_kernel<<<(NPTS / BM) * JSPLIT, NTHR, 0, stream>>>(X, sq, out, cand_val, cand_idx);
  merge_kernel<<<NPTS / NTHR, NTHR, 0, stream>>>(cand_val, cand_idx, out);
}

// Round 2
// 26457.172 us; speedup vs baseline: 1.0120x; 1.0120x over previous
//
#include <hip/hip_runtime.h>
#include <math.h>

// KNNGraph(2) on N=16384 points, D=64, fp32.
// adjacency = I + one-hot(nearest other neighbor) per row.
// argmin_j (sq[j] - 2*dot(x_i,x_j)), j != i  (sq[i] term is row-constant).
//
// R1 restructure: knn_kernel previously interleaved a 1.07-GB zero-store
// stream with its tile loads and showed 64 GB (!) of HBM traffic at 1.9%
// VALUBusy. Output zeroing now lives in a dedicated streaming kernel;
// knn_kernel touches only X (4 MB, L2-resident) + 256 KB of candidates.

#define NPTS 16384
#define DIM 64
#define BM 128          // rows per block
#define BN 64           // cols per j-tile
#define TM 8            // rows per thread
#define TN 4            // cols per thread
#define NTHR 256        // 16x16 thread layout
#define JSPLIT 4        // split j-range for occupancy (2 blocks/CU)
#define JRANGE (NPTS / JSPLIT)   // 4096
#define NJT (JRANGE / BN)        // 64 tiles
#define LS 68           // LDS row stride in floats: 272 B = 16B aligned, bank-spread

__global__ void zero_kernel(float4* __restrict__ out) {
  // Pure streaming zero of the 1.07-GB adjacency matrix. 2048 blocks x 256
  // threads, grid-stride, 16 B/lane coalesced stores -> near write-BW peak.
  const size_t total = (size_t)NPTS * NPTS / 4;   // float4 count
  size_t idx = (size_t)blockIdx.x * NTHR + threadIdx.x;
  const size_t stride = (size_t)gridDim.x * NTHR;
  const float4 z = make_float4(0.f, 0.f, 0.f, 0.f);
  for (size_t k = idx; k < total; k += stride) out[k] = z;
}

__global__ void sq_kernel(const float* __restrict__ X, float* __restrict__ sqout) {
  int i = blockIdx.x * NTHR + threadIdx.x;
  const float4* x4 = (const float4*)(X + (size_t)i * DIM);
  float s = 0.f;
#pragma unroll
  for (int k = 0; k < DIM / 4; ++k) {
    float4 v = x4[k];
    s = fmaf(v.x, v.x, s); s = fmaf(v.y, v.y, s);
    s = fmaf(v.z, v.z, s); s = fmaf(v.w, v.w, s);
  }
  sqout[i] = s;
}

__global__ __launch_bounds__(NTHR, 2) void knn_kernel(
    const float* __restrict__ X, const float* __restrict__ sqn,
    float* __restrict__ cand_val, int* __restrict__ cand_idx) {
  __shared__ float As[BM * LS];   // 34816 B
  __shared__ float Bs[BN * LS];   // 17408 B
  __shared__ float sqt[BN];

  const int tid = threadIdx.x;
  const int tx = tid & 15;
  const int ty = tid >> 4;
  const int ib = blockIdx.x >> 2;   // / JSPLIT
  const int jh = blockIdx.x & 3;    // % JSPLIT
  const int i0 = ib * BM;
  const int j0base = jh * JRANGE;

  // Stage A tile (BM x DIM) once: coalesced float4 loads.
  {
    const float4* src = (const float4*)(X + (size_t)i0 * DIM);
#pragma unroll
    for (int p = 0; p < (BM * DIM / 4) / NTHR; ++p) {
      int f4 = tid + NTHR * p;
      int r = f4 >> 4, c = f4 & 15;   // 16 float4 per row
      float4 v = src[f4];
      *(float4*)(&As[r * LS + c * 4]) = v;
    }
  }

  float bestv[TM];
  int besti[TM];
#pragma unroll
  for (int mk = 0; mk < TM; ++mk) { bestv[mk] = INFINITY; besti[mk] = 0x7fffffff; }

  for (int jt = 0; jt < NJT; ++jt) {
    const int j0 = j0base + jt * BN;
    __syncthreads();   // protect Bs from previous iteration's readers
    // Stage B tile (BN x DIM)
    {
      const float4* src = (const float4*)(X + (size_t)j0 * DIM);
#pragma unroll
      for (int p = 0; p < (BN * DIM / 4) / NTHR; ++p) {
        int f4 = tid + NTHR * p;
        int r = f4 >> 4, c = f4 & 15;
        float4 v = src[f4];
        *(float4*)(&Bs[r * LS + c * 4]) = v;
      }
      if (tid < BN) sqt[tid] = sqn[j0 + tid];
    }
    __syncthreads();

    float acc[TM][TN];
#pragma unroll
    for (int mk = 0; mk < TM; ++mk)
#pragma unroll
      for (int nk = 0; nk < TN; ++nk) acc[mk][nk] = 0.f;

#pragma unroll
    for (int d0 = 0; d0 < DIM; d0 += 4) {
      float4 a[TM], b[TN];
#pragma unroll
      for (int mk = 0; mk < TM; ++mk)
        a[mk] = *(const float4*)(&As[(ty + 16 * mk) * LS + d0]);
#pragma unroll
      for (int nk = 0; nk < TN; ++nk)
        b[nk] = *(const float4*)(&Bs[(tx + 16 * nk) * LS + d0]);
#pragma unroll
      for (int mk = 0; mk < TM; ++mk)
#pragma unroll
        for (int nk = 0; nk < TN; ++nk) {
          acc[mk][nk] = fmaf(a[mk].x, b[nk].x, acc[mk][nk]);
          acc[mk][nk] = fmaf(a[mk].y, b[nk].y, acc[mk][nk]);
          acc[mk][nk] = fmaf(a[mk].z, b[nk].z, acc[mk][nk]);
          acc[mk][nk] = fmaf(a[mk].w, b[nk].w, acc[mk][nk]);
        }
    }

    // Update running argmin (j visited in increasing order per thread).
#pragma unroll
    for (int nk = 0; nk < TN; ++nk) {
      const int j = j0 + tx + 16 * nk;
      const float sj = sqt[tx + 16 * nk];
#pragma unroll
      for (int mk = 0; mk < TM; ++mk) {
        const int irow = i0 + ty + 16 * mk;
        float v = fmaf(-2.f, acc[mk][nk], sj);
        if (j != irow && (v < bestv[mk] || (v == bestv[mk] && j < besti[mk]))) {
          bestv[mk] = v;
          besti[mk] = j;
        }
      }
    }
  }

  // Cross-thread reduction: row m is owned by the 16 tx-threads of its ty.
  __syncthreads();
  float* rv = As;        // [BM][16] floats (8 KB, fits in As)
  int* ri = (int*)Bs;    // [BM][16] ints  (8 KB, fits in Bs)
#pragma unroll
  for (int mk = 0; mk < TM; ++mk) {
    int m = ty + 16 * mk;
    rv[m * 16 + tx] = bestv[mk];
    ri[m * 16 + tx] = besti[mk];
  }
  __syncthreads();
  if (tid < BM) {
    float bv = INFINITY;
    int bi = 0x7fffffff;
#pragma unroll
    for (int t = 0; t < 16; ++t) {
      float v = rv[tid * 16 + t];
      int ix = ri[tid * 16 + t];
      if (v < bv || (v == bv && ix < bi)) { bv = v; bi = ix; }
    }
    cand_val[(size_t)(i0 + tid) * JSPLIT + jh] = bv;
    cand_idx[(size_t)(i0 + tid) * JSPLIT + jh] = bi;
  }
}

__global__ void merge_kernel(const float* __restrict__ cand_val,
                             const int* __restrict__ cand_idx,
                             float* __restrict__ out) {
  int i = blockIdx.x * NTHR + threadIdx.x;
  float bv = INFINITY;
  int bi = 0x7fffffff;
#pragma unroll
  for (int s = 0; s < JSPLIT; ++s) {
    float v = cand_val[(size_t)i * JSPLIT + s];
    int ix = cand_idx[(size_t)i * JSPLIT + s];
    if (v < bv || (v == bv && ix < bi)) { bv = v; bi = ix; }
  }
  out[(size_t)i * NPTS + i] = 1.0f;   // self is always nearest (dist ~ 0)
  out[(size_t)i * NPTS + bi] = 1.0f;  // nearest other neighbor
}

extern "C" void kernel_launch(void* const* d_in, const int* in_sizes, int n_in,
                              void* d_out, int out_size, void* d_ws, size_t ws_size,
                              hipStream_t stream) {
  const float* X = (const float*)d_in[0];
  float* out = (float*)d_out;

  // Workspace layout: sq[N] | cand_val[N*JSPLIT] | cand_idx[N*JSPLIT]  (~576 KB)
  float* sq = (float*)d_ws;
  float* cand_val = sq + NPTS;
  int* cand_idx = (int*)(cand_val + (size_t)NPTS * JSPLIT);

  zero_kernel<<<2048, NTHR, 0, stream>>>((float4*)out);
  sq_kernel<<<NPTS / NTHR, NTHR, 0, stream>>>(X, sq);
  knn_kernel<<<(NPTS / BM) * JSPLIT, NTHR, 0, stream>>>(X, sq, cand_val, cand_idx);
  merge_kernel<<<NPTS / NTHR, NTHR, 0, stream>>>(cand_val, cand_idx, out);
}

// Round 3
// 1707.214 us; speedup vs baseline: 15.6829x; 15.4973x over previous
//
#include <hip/hip_runtime.h>
#include <math.h>

// KNNGraph(2) on N=16384 points, D=64, fp32.
// adjacency = I + one-hot(nearest other neighbor) per row.
// argmin_j (sq[j] - 2*dot(x_i,x_j)), j != i  (sq[i] term is row-constant).
//
// R2 restructure: R1 showed 61.5 GB HBM traffic/dispatch with only ~0.5 GB
// logical footprint -> scratch spill of the inner-loop working set
// (acc[8][4] + a[8]/b[4] float4 arrays, fully-unrolled 16-step d0 loop).
// Now: only b[4] stays resident; A-fragments stream one float4 at a time;
// unrolling capped (jt: unroll 1, d0: unroll 2) to bound live ranges.

#define NPTS 16384
#define DIM 64
#define BM 128          // rows per block
#define BN 64           // cols per j-tile
#define TM 8            // rows per thread
#define TN 4            // cols per thread
#define NTHR 256        // 16x16 thread layout
#define JSPLIT 4        // split j-range for occupancy (2 blocks/CU)
#define JRANGE (NPTS / JSPLIT)   // 4096
#define NJT (JRANGE / BN)        // 64 tiles
#define LS 68           // LDS row stride in floats: 272 B = 16B aligned, bank-spread

__global__ void zero_kernel(float4* __restrict__ out) {
  // Pure streaming zero of the 1.07-GB adjacency matrix.
  const size_t total = (size_t)NPTS * NPTS / 4;   // float4 count
  size_t idx = (size_t)blockIdx.x * NTHR + threadIdx.x;
  const size_t stride = (size_t)gridDim.x * NTHR;
  const float4 z = make_float4(0.f, 0.f, 0.f, 0.f);
  for (size_t k = idx; k < total; k += stride) out[k] = z;
}

__global__ void sq_kernel(const float* __restrict__ X, float* __restrict__ sqout) {
  int i = blockIdx.x * NTHR + threadIdx.x;
  const float4* x4 = (const float4*)(X + (size_t)i * DIM);
  float s = 0.f;
#pragma unroll
  for (int k = 0; k < DIM / 4; ++k) {
    float4 v = x4[k];
    s = fmaf(v.x, v.x, s); s = fmaf(v.y, v.y, s);
    s = fmaf(v.z, v.z, s); s = fmaf(v.w, v.w, s);
  }
  sqout[i] = s;
}

__global__ __launch_bounds__(NTHR, 2) void knn_kernel(
    const float* __restrict__ X, const float* __restrict__ sqn,
    float* __restrict__ cand_val, int* __restrict__ cand_idx) {
  __shared__ float As[BM * LS];   // 34816 B
  __shared__ float Bs[BN * LS];   // 17408 B
  __shared__ float sqt[BN];

  const int tid = threadIdx.x;
  const int tx = tid & 15;
  const int ty = tid >> 4;
  const int ib = blockIdx.x >> 2;   // / JSPLIT
  const int jh = blockIdx.x & 3;    // % JSPLIT
  const int i0 = ib * BM;
  const int j0base = jh * JRANGE;

  // Stage A tile (BM x DIM) once: coalesced float4 loads.
  {
    const float4* src = (const float4*)(X + (size_t)i0 * DIM);
#pragma unroll
    for (int p = 0; p < (BM * DIM / 4) / NTHR; ++p) {
      int f4 = tid + NTHR * p;
      int r = f4 >> 4, c = f4 & 15;   // 16 float4 per row
      float4 v = src[f4];
      *(float4*)(&As[r * LS + c * 4]) = v;
    }
  }

  float bestv[TM];
  int besti[TM];
#pragma unroll
  for (int mk = 0; mk < TM; ++mk) { bestv[mk] = INFINITY; besti[mk] = 0x7fffffff; }

#pragma unroll 1   // keep the tile loop a real loop: bound register live ranges
  for (int jt = 0; jt < NJT; ++jt) {
    const int j0 = j0base + jt * BN;
    __syncthreads();   // protect Bs from previous iteration's readers
    // Stage B tile (BN x DIM)
    {
      const float4* src = (const float4*)(X + (size_t)j0 * DIM);
#pragma unroll
      for (int p = 0; p < (BN * DIM / 4) / NTHR; ++p) {
        int f4 = tid + NTHR * p;
        int r = f4 >> 4, c = f4 & 15;
        float4 v = src[f4];
        *(float4*)(&Bs[r * LS + c * 4]) = v;
      }
      if (tid < BN) sqt[tid] = sqn[j0 + tid];
    }
    __syncthreads();

    float acc[TM][TN];
#pragma unroll
    for (int mk = 0; mk < TM; ++mk)
#pragma unroll
      for (int nk = 0; nk < TN; ++nk) acc[mk][nk] = 0.f;

    // Register-lean GEMM: keep only b[4] (16 VGPRs) resident per d0-step,
    // stream A-fragments one float4 at a time. Live set ~85 VGPRs -> no
    // scratch even under a conservative allocator.
#pragma unroll 2
    for (int d0 = 0; d0 < DIM; d0 += 4) {
      float4 b[TN];
#pragma unroll
      for (int nk = 0; nk < TN; ++nk)
        b[nk] = *(const float4*)(&Bs[(tx + 16 * nk) * LS + d0]);
#pragma unroll
      for (int mk = 0; mk < TM; ++mk) {
        float4 av = *(const float4*)(&As[(ty + 16 * mk) * LS + d0]);
#pragma unroll
        for (int nk = 0; nk < TN; ++nk) {
          acc[mk][nk] = fmaf(av.x, b[nk].x, acc[mk][nk]);
          acc[mk][nk] = fmaf(av.y, b[nk].y, acc[mk][nk]);
          acc[mk][nk] = fmaf(av.z, b[nk].z, acc[mk][nk]);
          acc[mk][nk] = fmaf(av.w, b[nk].w, acc[mk][nk]);
        }
      }
    }

    // Update running argmin (j visited in increasing order per thread).
#pragma unroll
    for (int nk = 0; nk < TN; ++nk) {
      const int j = j0 + tx + 16 * nk;
      const float sj = sqt[tx + 16 * nk];
#pragma unroll
      for (int mk = 0; mk < TM; ++mk) {
        const int irow = i0 + ty + 16 * mk;
        float v = fmaf(-2.f, acc[mk][nk], sj);
        if (j != irow && (v < bestv[mk] || (v == bestv[mk] && j < besti[mk]))) {
          bestv[mk] = v;
          besti[mk] = j;
        }
      }
    }
  }

  // Cross-thread reduction: row m is owned by the 16 tx-threads of its ty.
  __syncthreads();
  float* rv = As;        // [BM][16] floats (8 KB, fits in As)
  int* ri = (int*)Bs;    // [BM][16] ints  (8 KB, fits in Bs)
#pragma unroll
  for (int mk = 0; mk < TM; ++mk) {
    int m = ty + 16 * mk;
    rv[m * 16 + tx] = bestv[mk];
    ri[m * 16 + tx] = besti[mk];
  }
  __syncthreads();
  if (tid < BM) {
    float bv = INFINITY;
    int bi = 0x7fffffff;
#pragma unroll
    for (int t = 0; t < 16; ++t) {
      float v = rv[tid * 16 + t];
      int ix = ri[tid * 16 + t];
      if (v < bv || (v == bv && ix < bi)) { bv = v; bi = ix; }
    }
    cand_val[(size_t)(i0 + tid) * JSPLIT + jh] = bv;
    cand_idx[(size_t)(i0 + tid) * JSPLIT + jh] = bi;
  }
}

__global__ void merge_kernel(const float* __restrict__ cand_val,
                             const int* __restrict__ cand_idx,
                             float* __restrict__ out) {
  int i = blockIdx.x * NTHR + threadIdx.x;
  float bv = INFINITY;
  int bi = 0x7fffffff;
#pragma unroll
  for (int s = 0; s < JSPLIT; ++s) {
    float v = cand_val[(size_t)i * JSPLIT + s];
    int ix = cand_idx[(size_t)i * JSPLIT + s];
    if (v < bv || (v == bv && ix < bi)) { bv = v; bi = ix; }
  }
  out[(size_t)i * NPTS + i] = 1.0f;   // self is always nearest (dist ~ 0)
  out[(size_t)i * NPTS + bi] = 1.0f;  // nearest other neighbor
}

extern "C" void kernel_launch(void* const* d_in, const int* in_sizes, int n_in,
                              void* d_out, int out_size, void* d_ws, size_t ws_size,
                              hipStream_t stream) {
  const float* X = (const float*)d_in[0];
  float* out = (float*)d_out;

  // Workspace layout: sq[N] | cand_val[N*JSPLIT] | cand_idx[N*JSPLIT]  (~576 KB)
  float* sq = (float*)d_ws;
  float* cand_val = sq + NPTS;
  int* cand_idx = (int*)(cand_val + (size_t)NPTS * JSPLIT);

  zero_kernel<<<2048, NTHR, 0, stream>>>((float4*)out);
  sq_kernel<<<NPTS / NTHR, NTHR, 0, stream>>>(X, sq);
  knn_kernel<<<(NPTS / BM) * JSPLIT, NTHR, 0, stream>>>(X, sq, cand_val, cand_idx);
  merge_kernel<<<NPTS / NTHR, NTHR, 0, stream>>>(cand_val, cand_idx, out);
}

// Round 4
// 1490.146 us; speedup vs baseline: 17.9674x; 1.1457x over previous
//
#include <hip/hip_runtime.h>
#include <math.h>

// KNNGraph(2) on N=16384 points, D=64, fp32.
// adjacency = I + one-hot(nearest other neighbor) per row.
// argmin_j (sq[j] - 2*dot(x_i,x_j)), j != i  (sq[i] term is row-constant).
//
// R2: fixed catastrophic scratch spill (61.5 GB HBM -> 12 MB, 25.5ms -> 717us)
//     by keeping only b[4] resident and capping unroll.
// R3: fold output zeroing back into knn_kernel. knn runs at 0.2% HBM util,
//     so the 1.07-GB zero stream hides under compute; removes zero_kernel's
//     ~270us serial pass. Stores issue after the barrier -> drain during the
//     GEMM, at the NEXT tile's barrier.

#define NPTS 16384
#define DIM 64
#define BM 128          // rows per block
#define BN 64           // cols per j-tile
#define TM 8            // rows per thread
#define TN 4            // cols per thread
#define NTHR 256        // 16x16 thread layout
#define JSPLIT 4        // split j-range for occupancy (2 blocks/CU)
#define JRANGE (NPTS / JSPLIT)   // 4096
#define NJT (JRANGE / BN)        // 64 tiles
#define LS 68           // LDS row stride in floats: 272 B = 16B aligned, bank-spread

__global__ void sq_kernel(const float* __restrict__ X, float* __restrict__ sqout) {
  int i = blockIdx.x * NTHR + threadIdx.x;
  const float4* x4 = (const float4*)(X + (size_t)i * DIM);
  float s = 0.f;
#pragma unroll
  for (int k = 0; k < DIM / 4; ++k) {
    float4 v = x4[k];
    s = fmaf(v.x, v.x, s); s = fmaf(v.y, v.y, s);
    s = fmaf(v.z, v.z, s); s = fmaf(v.w, v.w, s);
  }
  sqout[i] = s;
}

__global__ __launch_bounds__(NTHR, 2) void knn_kernel(
    const float* __restrict__ X, const float* __restrict__ sqn,
    float* __restrict__ out, float* __restrict__ cand_val, int* __restrict__ cand_idx) {
  __shared__ float As[BM * LS];   // 34816 B
  __shared__ float Bs[BN * LS];   // 17408 B
  __shared__ float sqt[BN];

  const int tid = threadIdx.x;
  const int tx = tid & 15;
  const int ty = tid >> 4;
  const int ib = blockIdx.x >> 2;   // / JSPLIT
  const int jh = blockIdx.x & 3;    // % JSPLIT
  const int i0 = ib * BM;
  const int j0base = jh * JRANGE;

  // Stage A tile (BM x DIM) once: coalesced float4 loads.
  {
    const float4* src = (const float4*)(X + (size_t)i0 * DIM);
#pragma unroll
    for (int p = 0; p < (BM * DIM / 4) / NTHR; ++p) {
      int f4 = tid + NTHR * p;
      int r = f4 >> 4, c = f4 & 15;   // 16 float4 per row
      float4 v = src[f4];
      *(float4*)(&As[r * LS + c * 4]) = v;
    }
  }

  float bestv[TM];
  int besti[TM];
#pragma unroll
  for (int mk = 0; mk < TM; ++mk) { bestv[mk] = INFINITY; besti[mk] = 0x7fffffff; }

#pragma unroll 1   // keep the tile loop a real loop: bound register live ranges
  for (int jt = 0; jt < NJT; ++jt) {
    const int j0 = j0base + jt * BN;
    __syncthreads();   // protect Bs from previous iteration's readers
    // Stage B tile (BN x DIM)
    {
      const float4* src = (const float4*)(X + (size_t)j0 * DIM);
#pragma unroll
      for (int p = 0; p < (BN * DIM / 4) / NTHR; ++p) {
        int f4 = tid + NTHR * p;
        int r = f4 >> 4, c = f4 & 15;
        float4 v = src[f4];
        *(float4*)(&Bs[r * LS + c * 4]) = v;
      }
      if (tid < BN) sqt[tid] = sqn[j0 + tid];
    }
    __syncthreads();

    // Zero this block's output stripe (BM x BN) for this tile. Issued after
    // the barrier: stores drain during the GEMM below (vmcnt(0) only at the
    // NEXT tile's barrier). knn is at 0.2% HBM util -> this rides for free.
    {
#pragma unroll
      for (int p = 0; p < (BM * BN / 4) / NTHR; ++p) {
        int f4 = tid + NTHR * p;
        int r = f4 >> 4;      // 16 float4 per row
        int c = f4 & 15;
        *(float4*)(out + (size_t)(i0 + r) * NPTS + j0 + c * 4) =
            make_float4(0.f, 0.f, 0.f, 0.f);
      }
    }

    float acc[TM][TN];
#pragma unroll
    for (int mk = 0; mk < TM; ++mk)
#pragma unroll
      for (int nk = 0; nk < TN; ++nk) acc[mk][nk] = 0.f;

    // Register-lean GEMM: keep only b[4] (16 VGPRs) resident per d0-step,
    // stream A-fragments one float4 at a time. Live set ~85 VGPRs -> no
    // scratch even under a conservative allocator.
#pragma unroll 2
    for (int d0 = 0; d0 < DIM; d0 += 4) {
      float4 b[TN];
#pragma unroll
      for (int nk = 0; nk < TN; ++nk)
        b[nk] = *(const float4*)(&Bs[(tx + 16 * nk) * LS + d0]);
#pragma unroll
      for (int mk = 0; mk < TM; ++mk) {
        float4 av = *(const float4*)(&As[(ty + 16 * mk) * LS + d0]);
#pragma unroll
        for (int nk = 0; nk < TN; ++nk) {
          acc[mk][nk] = fmaf(av.x, b[nk].x, acc[mk][nk]);
          acc[mk][nk] = fmaf(av.y, b[nk].y, acc[mk][nk]);
          acc[mk][nk] = fmaf(av.z, b[nk].z, acc[mk][nk]);
          acc[mk][nk] = fmaf(av.w, b[nk].w, acc[mk][nk]);
        }
      }
    }

    // Update running argmin (j visited in increasing order per thread).
#pragma unroll
    for (int nk = 0; nk < TN; ++nk) {
      const int j = j0 + tx + 16 * nk;
      const float sj = sqt[tx + 16 * nk];
#pragma unroll
      for (int mk = 0; mk < TM; ++mk) {
        const int irow = i0 + ty + 16 * mk;
        float v = fmaf(-2.f, acc[mk][nk], sj);
        if (j != irow && (v < bestv[mk] || (v == bestv[mk] && j < besti[mk]))) {
          bestv[mk] = v;
          besti[mk] = j;
        }
      }
    }
  }

  // Cross-thread reduction: row m is owned by the 16 tx-threads of its ty.
  __syncthreads();
  float* rv = As;        // [BM][16] floats (8 KB, fits in As)
  int* ri = (int*)Bs;    // [BM][16] ints  (8 KB, fits in Bs)
#pragma unroll
  for (int mk = 0; mk < TM; ++mk) {
    int m = ty + 16 * mk;
    rv[m * 16 + tx] = bestv[mk];
    ri[m * 16 + tx] = besti[mk];
  }
  __syncthreads();
  if (tid < BM) {
    float bv = INFINITY;
    int bi = 0x7fffffff;
#pragma unroll
    for (int t = 0; t < 16; ++t) {
      float v = rv[tid * 16 + t];
      int ix = ri[tid * 16 + t];
      if (v < bv || (v == bv && ix < bi)) { bv = v; bi = ix; }
    }
    cand_val[(size_t)(i0 + tid) * JSPLIT + jh] = bv;
    cand_idx[(size_t)(i0 + tid) * JSPLIT + jh] = bi;
  }
}

__global__ void merge_kernel(const float* __restrict__ cand_val,
                             const int* __restrict__ cand_idx,
                             float* __restrict__ out) {
  int i = blockIdx.x * NTHR + threadIdx.x;
  float bv = INFINITY;
  int bi = 0x7fffffff;
#pragma unroll
  for (int s = 0; s < JSPLIT; ++s) {
    float v = cand_val[(size_t)i * JSPLIT + s];
    int ix = cand_idx[(size_t)i * JSPLIT + s];
    if (v < bv || (v == bv && ix < bi)) { bv = v; bi = ix; }
  }
  out[(size_t)i * NPTS + i] = 1.0f;   // self is always nearest (dist ~ 0)
  out[(size_t)i * NPTS + bi] = 1.0f;  // nearest other neighbor
}

extern "C" void kernel_launch(void* const* d_in, const int* in_sizes, int n_in,
                              void* d_out, int out_size, void* d_ws, size_t ws_size,
                              hipStream_t stream) {
  const float* X = (const float*)d_in[0];
  float* out = (float*)d_out;

  // Workspace layout: sq[N] | cand_val[N*JSPLIT] | cand_idx[N*JSPLIT]  (~576 KB)
  float* sq = (float*)d_ws;
  float* cand_val = sq + NPTS;
  int* cand_idx = (int*)(cand_val + (size_t)NPTS * JSPLIT);

  sq_kernel<<<NPTS / NTHR, NTHR, 0, stream>>>(X, sq);
  knn_kernel<<<(NPTS / BM) * JSPLIT, NTHR, 0, stream>>>(X, sq, out, cand_val, cand_idx);
  merge_kernel<<<NPTS / NTHR, NTHR, 0, stream>>>(cand_val, cand_idx, out);
}